// Round 11
// baseline (42.328 us; speedup 1.0000x reference)
//
#include <hip/hip_runtime.h>

#define H 32
#define C 64
#define K 15
#define SIGMA 0.3f

// ---------- Kernel A: neighbor -> (nearest kernel point, influence), compacted to ws ----------
__global__ __launch_bounds__(256) void kpconv_phaseA(
    const float* __restrict__ q_pts,
    const float* __restrict__ s_pts,
    const int*   __restrict__ inds,
    const float* __restrict__ kpts,
    int*         __restrict__ cnt,       // [N]
    float2*      __restrict__ entries,   // [N][32], 256B row stride
    int N)
{
    const int tid  = threadIdx.x;
    const int wave = tid >> 6;
    const int lane = tid & 63;
    const int half = lane >> 5;          // query within the wave
    const int hl   = lane & 31;          // neighbor slot

    // wave-uniform kernel points -> SGPRs via s_load
    float kp[K * 3];
    #pragma unroll
    for (int i = 0; i < K * 3; ++i) kp[i] = kpts[i];

    const int m = (blockIdx.x * 4 + wave) * 2 + half;   // 8 queries / block

    float infl   = 0.0f;
    int   packed = 0;
    if (m < N) {
        const int idx = inds[m * H + hl];        // coalesced 128B per half
        if (idx >= 0 && idx < N) {
            const float qx = q_pts[m * 3 + 0];
            const float qy = q_pts[m * 3 + 1];
            const float qz = q_pts[m * 3 + 2];
            const float nx = s_pts[idx * 3 + 0] - qx;
            const float ny = s_pts[idx * 3 + 1] - qy;
            const float nz = s_pts[idx * 3 + 2] - qz;
            float best = 1e30f;
            int   kbest = 0;
            #pragma unroll
            for (int k = 0; k < K; ++k) {        // math bit-identical to R6
                const float dx = nx - kp[k * 3 + 0];
                const float dy = ny - kp[k * 3 + 1];
                const float dz = nz - kp[k * 3 + 2];
                const float d2 = dx * dx + dy * dy + dz * dz;
                if (d2 < best) { best = d2; kbest = k; }
            }
            infl = 1.0f - __builtin_amdgcn_sqrtf(best) * (1.0f / SIGMA);
            if (infl < 0.0f) infl = 0.0f;
            packed = idx | (kbest << 20);
        }
    }

    const unsigned long long ball = __ballot(infl > 0.0f);
    const unsigned int lo = (unsigned int)(ball & 0xFFFFFFFFu);
    const unsigned int hi = (unsigned int)(ball >> 32);
    const unsigned int maskH = half ? hi : lo;
    const int rank = __popc(maskH & ((1u << hl) - 1u));

    if (infl > 0.0f)
        entries[(size_t)m * 32 + rank] = make_float2(__int_as_float(packed), infl);
    if (hl == 0 && m < N)
        cnt[m] = __popc(maskH);
}

// ---------- Kernel B: gather features/weights per compacted entry, accumulate ----------
__global__ __launch_bounds__(256) void kpconv_phaseB(
    const float*  __restrict__ s_feats,
    const float*  __restrict__ weights,
    const int*    __restrict__ cnt,
    const float2* __restrict__ entries,
    float*        __restrict__ out,
    int N)
{
    const int tid  = threadIdx.x;
    const int wave = tid >> 6;
    const int lane = tid & 63;
    const int q    = lane >> 4;          // which of the wave's 4 queries
    const int ql   = lane & 15;          // channel group (4 channels)

    const int mq = (blockIdx.x * 4 + wave) * 4 + q;   // 16 queries / block
    const int cq = (mq < N) ? cnt[mq] : 0;

    const float4* row = (const float4*)(entries + (size_t)mq * 32);
    float4 acc = make_float4(0.0f, 0.0f, 0.0f, 0.0f);

    for (int i = 0; i < cq; i += 2) {
        const float4 pf = row[i >> 1];               // 2 entries, broadcast in qwave
        const int   p0   = __float_as_int(pf.x);
        const float f0   = pf.y;
        const bool  has1 = (i + 1) < cq;
        const int   p1   = has1 ? __float_as_int(pf.z) : 0;   // row 0: hot line
        const float f1   = has1 ? pf.w : 0.0f;
        const float4 a0 = *(const float4*)(s_feats + (size_t)(p0 & 0xFFFFF) * C + ql * 4);
        const float4 w0 = *(const float4*)(weights + (p0 >> 20) * C + ql * 4);
        const float4 a1 = *(const float4*)(s_feats + (size_t)(p1 & 0xFFFFF) * C + ql * 4);
        const float4 w1 = *(const float4*)(weights + (p1 >> 20) * C + ql * 4);
        acc.x += a0.x * w0.x * f0;  acc.y += a0.y * w0.y * f0;
        acc.z += a0.z * w0.z * f0;  acc.w += a0.w * w0.w * f0;
        acc.x += a1.x * w1.x * f1;  acc.y += a1.y * w1.y * f1;
        acc.z += a1.z * w1.z * f1;  acc.w += a1.w * w1.w * f1;
    }

    if (mq < N)
        *(float4*)(out + (size_t)mq * C + ql * 4) = acc;   // 256B per query
}

// ---------- Fallback: single-kernel R6 (best known) if ws is too small ----------
#define WAVES 4
#define QPW 4
__global__ __launch_bounds__(256) void kpconv_fused(
    const float* __restrict__ q_pts,
    const float* __restrict__ s_pts,
    const float* __restrict__ s_feats,
    const int*   __restrict__ inds,
    const float* __restrict__ weights,
    const float* __restrict__ kpts,
    float*       __restrict__ out,
    int N)
{
    __shared__ float2 list[WAVES][QPW][34];

    const int tid  = threadIdx.x;
    const int wave = tid >> 6;
    const int lane = tid & 63;
    const int half = lane >> 5;
    const int hl   = lane & 31;

    float kp[K * 3];
    #pragma unroll
    for (int i = 0; i < K * 3; ++i) kp[i] = kpts[i];

    const int qBase = (blockIdx.x * WAVES + wave) * QPW;
    int c0 = 0, c1 = 0, c2 = 0, c3 = 0;

    #pragma unroll
    for (int p = 0; p < 2; ++p) {
        const int m = qBase + p * 2 + half;
        float infl = 0.0f;
        int   packed = 0;
        if (m < N) {
            const int idx = inds[m * H + hl];
            if (idx >= 0 && idx < N) {
                const float qx = q_pts[m * 3 + 0];
                const float qy = q_pts[m * 3 + 1];
                const float qz = q_pts[m * 3 + 2];
                const float nx = s_pts[idx * 3 + 0] - qx;
                const float ny = s_pts[idx * 3 + 1] - qy;
                const float nz = s_pts[idx * 3 + 2] - qz;
                float best = 1e30f;
                int   kbest = 0;
                #pragma unroll
                for (int k = 0; k < K; ++k) {
                    const float dx = nx - kp[k * 3 + 0];
                    const float dy = ny - kp[k * 3 + 1];
                    const float dz = nz - kp[k * 3 + 2];
                    const float d2 = dx * dx + dy * dy + dz * dz;
                    if (d2 < best) { best = d2; kbest = k; }
                }
                infl = 1.0f - __builtin_amdgcn_sqrtf(best) * (1.0f / SIGMA);
                if (infl < 0.0f) infl = 0.0f;
                packed = idx | (kbest << 20);
            }
        }
        const unsigned long long ball = __ballot(infl > 0.0f);
        const unsigned int lo = (unsigned int)(ball & 0xFFFFFFFFu);
        const unsigned int hi = (unsigned int)(ball >> 32);
        const unsigned int maskH = half ? hi : lo;
        const int rank = __popc(maskH & ((1u << hl) - 1u));
        if (infl > 0.0f)
            list[wave][p * 2 + half][rank] = make_float2(__int_as_float(packed), infl);
        if (p == 0) { c0 = __popc(lo); c1 = __popc(hi); }
        else        { c2 = __popc(lo); c3 = __popc(hi); }
    }

    const int q  = lane >> 4;
    const int ql = lane & 15;
    const int cq = (q < 2) ? (q == 0 ? c0 : c1) : (q == 2 ? c2 : c3);
    int maxc = c0 > c1 ? c0 : c1;
    if (c2 > maxc) maxc = c2;
    if (c3 > maxc) maxc = c3;

    float4 acc = make_float4(0.0f, 0.0f, 0.0f, 0.0f);
    for (int i = 0; i < maxc; i += 2) {
        if (i < cq) {
            const float4 pf = *(const float4*)&list[wave][q][i];
            const int   p0   = __float_as_int(pf.x);
            const float f0   = pf.y;
            const bool  has1 = (i + 1) < cq;
            const int   p1   = has1 ? __float_as_int(pf.z) : 0;
            const float f1   = has1 ? pf.w : 0.0f;
            const float4 a0 = *(const float4*)(s_feats + (size_t)(p0 & 0xFFFFF) * C + ql * 4);
            const float4 w0 = *(const float4*)(weights + (p0 >> 20) * C + ql * 4);
            const float4 a1 = *(const float4*)(s_feats + (size_t)(p1 & 0xFFFFF) * C + ql * 4);
            const float4 w1 = *(const float4*)(weights + (p1 >> 20) * C + ql * 4);
            acc.x += a0.x * w0.x * f0;  acc.y += a0.y * w0.y * f0;
            acc.z += a0.z * w0.z * f0;  acc.w += a0.w * w0.w * f0;
            acc.x += a1.x * w1.x * f1;  acc.y += a1.y * w1.y * f1;
            acc.z += a1.z * w1.z * f1;  acc.w += a1.w * w1.w * f1;
        }
    }

    const int mq = qBase + q;
    if (mq < N)
        *(float4*)(out + (size_t)mq * C + ql * 4) = acc;
}

extern "C" void kernel_launch(void* const* d_in, const int* in_sizes, int n_in,
                              void* d_out, int out_size, void* d_ws, size_t ws_size,
                              hipStream_t stream) {
    const float* q_pts   = (const float*)d_in[0];
    const float* s_pts   = (const float*)d_in[1];
    const float* s_feats = (const float*)d_in[2];
    const int*   inds    = (const int*)d_in[3];
    const float* weights = (const float*)d_in[4];
    const float* kpts    = (const float*)d_in[5];
    float* out = (float*)d_out;

    const int N = in_sizes[0] / 3;               // q_pts is (N,3)

    const size_t entOff  = 1 << 20;                       // entries at +1 MB
    const size_t wsNeed  = entOff + (size_t)N * 32 * sizeof(float2);

    if (ws_size >= wsNeed) {
        int*    cnt     = (int*)d_ws;
        float2* entries = (float2*)((char*)d_ws + entOff);
        const int blocksA = (N + 7) / 8;                  // 8 q / block
        const int blocksB = (N + 15) / 16;                // 16 q / block
        kpconv_phaseA<<<blocksA, 256, 0, stream>>>(q_pts, s_pts, inds, kpts,
                                                   cnt, entries, N);
        kpconv_phaseB<<<blocksB, 256, 0, stream>>>(s_feats, weights, cnt,
                                                   entries, out, N);
    } else {
        const int qpb = WAVES * QPW;
        const int blocks = (N + qpb - 1) / qpb;
        kpconv_fused<<<blocks, 256, 0, stream>>>(q_pts, s_pts, s_feats, inds,
                                                 weights, kpts, out, N);
    }
}

// Round 12
// 32.721 us; speedup vs baseline: 1.2936x; 1.2936x over previous
//
#include <hip/hip_runtime.h>

#define H 32
#define C 64
#define K 15
#define SIGMA 0.3f
#define WAVES 2          // waves per block (block = 128): finer slot granularity
#define QPW 4            // queries per wave

__global__ __launch_bounds__(128) void kpconv_kernel(
    const float* __restrict__ q_pts,
    const float* __restrict__ s_pts,
    const float* __restrict__ s_feats,
    const int*   __restrict__ inds,
    const float* __restrict__ weights,
    const float* __restrict__ kpts,
    float*       __restrict__ out,
    int N)
{
    // padded row (34 float2 = 272 B): q-rows stay 16B-aligned
    __shared__ float2 list[WAVES][QPW][34];   // ~2.2 KB

    const int tid  = threadIdx.x;
    const int wave = tid >> 6;
    const int lane = tid & 63;
    const int half = lane >> 5;          // query within the pass
    const int hl   = lane & 31;          // neighbor slot

    // wave-uniform kernel points -> SGPRs via s_load
    float kp[K * 3];
    #pragma unroll
    for (int i = 0; i < K * 3; ++i) kp[i] = kpts[i];

    const int qBase = (blockIdx.x * WAVES + wave) * QPW;

    int c0 = 0, c1 = 0, c2 = 0, c3 = 0;  // active counts, wave-uniform

    // ---- Phase A: two passes, each pass = 2 queries x 32 neighbors ----
    // (sequential passes: R9 showed fusing these chains costs +1.6us)
    #pragma unroll
    for (int p = 0; p < 2; ++p) {
        const int m = qBase + p * 2 + half;
        float infl = 0.0f;
        int   packed = 0;
        if (m < N) {
            const int idx = inds[m * H + hl];    // coalesced
            if (idx >= 0 && idx < N) {
                const float qx = q_pts[m * 3 + 0];
                const float qy = q_pts[m * 3 + 1];
                const float qz = q_pts[m * 3 + 2];
                const float nx = s_pts[idx * 3 + 0] - qx;
                const float ny = s_pts[idx * 3 + 1] - qy;
                const float nz = s_pts[idx * 3 + 2] - qz;
                float best = 1e30f;
                int   kbest = 0;
                #pragma unroll
                for (int k = 0; k < K; ++k) {    // math bit-identical to R6
                    const float dx = nx - kp[k * 3 + 0];
                    const float dy = ny - kp[k * 3 + 1];
                    const float dz = nz - kp[k * 3 + 2];
                    const float d2 = dx * dx + dy * dy + dz * dz;
                    if (d2 < best) { best = d2; kbest = k; }
                }
                infl = 1.0f - __builtin_amdgcn_sqrtf(best) * (1.0f / SIGMA);
                if (infl < 0.0f) infl = 0.0f;
                packed = idx | (kbest << 20);
            }
        }
        const unsigned long long ball = __ballot(infl > 0.0f);
        const unsigned int lo = (unsigned int)(ball & 0xFFFFFFFFu);
        const unsigned int hi = (unsigned int)(ball >> 32);
        const unsigned int maskH = half ? hi : lo;
        const int rank = __popc(maskH & ((1u << hl) - 1u));
        if (infl > 0.0f)
            list[wave][p * 2 + half][rank] = make_float2(__int_as_float(packed), infl);
        if (p == 0) { c0 = __popc(lo); c1 = __popc(hi); }
        else        { c2 = __popc(lo); c3 = __popc(hi); }
    }
    // same-wave LDS RAW: DS pipe is in-order per wave; no barrier needed.

    // ---- Phase B: quarter-wave per query, float4 channels, 2 pops/iter ----
    const int q  = lane >> 4;            // which of the 4 queries
    const int ql = lane & 15;            // channel group (4 channels)
    const int cq = (q < 2) ? (q == 0 ? c0 : c1) : (q == 2 ? c2 : c3);
    int maxc = c0 > c1 ? c0 : c1;
    if (c2 > maxc) maxc = c2;
    if (c3 > maxc) maxc = c3;

    float4 acc = make_float4(0.0f, 0.0f, 0.0f, 0.0f);
    for (int i = 0; i < maxc; i += 2) {
        if (i < cq) {
            const float4 pf = *(const float4*)&list[wave][q][i];  // 16B aligned
            const int   p0   = __float_as_int(pf.x);
            const float f0   = pf.y;
            const bool  has1 = (i + 1) < cq;
            const int   p1   = has1 ? __float_as_int(pf.z) : 0;   // row 0: hot line
            const float f1   = has1 ? pf.w : 0.0f;
            const float4 a0 = *(const float4*)(s_feats + (size_t)(p0 & 0xFFFFF) * C + ql * 4);
            const float4 w0 = *(const float4*)(weights + (p0 >> 20) * C + ql * 4);
            const float4 a1 = *(const float4*)(s_feats + (size_t)(p1 & 0xFFFFF) * C + ql * 4);
            const float4 w1 = *(const float4*)(weights + (p1 >> 20) * C + ql * 4);
            acc.x += a0.x * w0.x * f0;  acc.y += a0.y * w0.y * f0;
            acc.z += a0.z * w0.z * f0;  acc.w += a0.w * w0.w * f0;
            acc.x += a1.x * w1.x * f1;  acc.y += a1.y * w1.y * f1;
            acc.z += a1.z * w1.z * f1;  acc.w += a1.w * w1.w * f1;
        }
    }

    const int mq = qBase + q;
    if (mq < N)
        *(float4*)(out + (size_t)mq * C + ql * 4) = acc;   // 256B per query
}

extern "C" void kernel_launch(void* const* d_in, const int* in_sizes, int n_in,
                              void* d_out, int out_size, void* d_ws, size_t ws_size,
                              hipStream_t stream) {
    const float* q_pts   = (const float*)d_in[0];
    const float* s_pts   = (const float*)d_in[1];
    const float* s_feats = (const float*)d_in[2];
    const int*   inds    = (const int*)d_in[3];
    const float* weights = (const float*)d_in[4];
    const float* kpts    = (const float*)d_in[5];
    float* out = (float*)d_out;

    const int N = in_sizes[0] / 3;               // q_pts is (N,3)
    const int qpb = WAVES * QPW;                 // 8 queries per block
    const int blocks = (N + qpb - 1) / qpb;      // 12500
    kpconv_kernel<<<blocks, 128, 0, stream>>>(q_pts, s_pts, s_feats, inds,
                                              weights, kpts, out, N);
}